// Round 5
// baseline (33.422 us; speedup 1.0000x reference)
//
#include <hip/hip_runtime.h>

typedef unsigned int uint;
typedef unsigned short ushort;

#define BATCH 2048
#define INF_  512
#define OUTF  256

// ws layout (bytes): A16 | W16T | partials(f16)
#define A16_OFF  0
#define W16T_OFF ((size_t)BATCH * INF_ * 2)                 // 2 MB
#define PART_OFF (W16T_OFF + (size_t)OUTF * INF_ * 2)       // +256 KB
#define PLANE16  ((size_t)BATCH * OUTF * 2)                 // 1 MB per partial plane

__device__ __forceinline__ void gload16(const void* src, void* dst_lds) {
  __builtin_amdgcn_global_load_lds((const __attribute__((address_space(1))) void*)src,
                                   (__attribute__((address_space(3))) void*)dst_lds,
                                   16, 0, 0);
}

#define PKMIN(d, a, b) asm("v_pk_min_f16 %0, %1, %2" : "=v"(d) : "v"(a), "v"(b))
#define PKMAX(d, a, b) asm("v_pk_max_f16 %0, %1, %2" : "=v"(d) : "v"(a), "v"(b))
#define PKMAXA(d, a)   asm("v_pk_max_f16 %0, %0, %1" : "+v"(d) : "v"(a))

static __device__ __forceinline__ uint pkrtz(float a, float b) {
  typedef __fp16 half2_t __attribute__((ext_vector_type(2)));
  half2_t h = __builtin_amdgcn_cvt_pkrtz(a, b);
  return __builtin_bit_cast(uint, h);
}
static __device__ __forceinline__ float h2f(uint u) {
  __fp16 h = __builtin_bit_cast(__fp16, (ushort)(u & 0xFFFF));
  return (float)h;
}

// ---- pass 1: M -> f16 row-major; W -> f16 TRANSPOSED [o][k] ----
__global__ __launch_bounds__(256) void crisp_convert(const float* __restrict__ M,
                                                     const float* __restrict__ W,
                                                     ushort* __restrict__ A16,
                                                     ushort* __restrict__ W16T) {
  if (blockIdx.x < 512) {
    int gid = blockIdx.x * 256 + threadIdx.x;
    const float4* src = (const float4*)M;
    float4 v0 = src[gid * 2], v1 = src[gid * 2 + 1];
    uint4 o;
    o.x = pkrtz(v0.x, v0.y); o.y = pkrtz(v0.z, v0.w);
    o.z = pkrtz(v1.x, v1.y); o.w = pkrtz(v1.z, v1.w);
    ((uint4*)A16)[gid] = o;
  } else {
    int id = blockIdx.x - 512;  // 0..31: one 64x64 tile of W (512x256)
    int kt = id >> 2, ot = id & 3;
    __shared__ ushort tile[64][72];
    int t = threadIdx.x;
    int r = t >> 2, c0 = (t & 3) * 16;
    const float* wp = W + (size_t)(kt * 64 + r) * OUTF + ot * 64 + c0;
    float4 w0 = *(const float4*)(wp);
    float4 w1 = *(const float4*)(wp + 4);
    float4 w2 = *(const float4*)(wp + 8);
    float4 w3 = *(const float4*)(wp + 12);
    uint ps[8] = {pkrtz(w0.x, w0.y), pkrtz(w0.z, w0.w), pkrtz(w1.x, w1.y), pkrtz(w1.z, w1.w),
                  pkrtz(w2.x, w2.y), pkrtz(w2.z, w2.w), pkrtz(w3.x, w3.y), pkrtz(w3.z, w3.w)};
#pragma unroll
    for (int j = 0; j < 8; j++) {
      tile[r][c0 + 2 * j]     = (ushort)(ps[j] & 0xFFFF);
      tile[r][c0 + 2 * j + 1] = (ushort)(ps[j] >> 16);
    }
    __syncthreads();
    int o = t >> 2, k0 = (t & 3) * 16;
    uint w[8];
#pragma unroll
    for (int j = 0; j < 8; j++)
      w[j] = (uint)tile[k0 + 2 * j][o] | ((uint)tile[k0 + 2 * j + 1][o] << 16);
    ushort* dst = W16T + (size_t)(ot * 64 + o) * INF_ + kt * 64 + k0;
    *(uint4*)dst       = make_uint4(w[0], w[1], w[2], w[3]);
    *(uint4*)(dst + 8) = make_uint4(w[4], w[5], w[6], w[7]);
  }
}

// ---- pass 2: tropical partials, packed f16 ----
// 1-wave block, wave tile 64x64, per-thread 8x8, BK=32 (4 granule-slots of 8 f16).
// LDS layout (conflict-free): granule(row,slot) at index slot*64 + (row&7)*8 + (row>>3).
//   read av[r] -> g = kq*64 + r*8 + mg  : g%8 = mg (8 distinct bank-quads, og broadcast)
//   read bv[c] -> g = kq*64 + c*8 + og  : g%8 = og (mg broadcast)
// Staging inverse: batch i (=slot), lane -> row = og*8 + mg. No barriers (single wave).
template <int T>  // number of BK=32 steps per block; KS = 512/(32*T)
__global__ __launch_bounds__(64, 2) void crisp_partial16(const ushort* __restrict__ A16,
                                                         const ushort* __restrict__ W16T,
                                                         ushort* __restrict__ part) {
  __shared__ uint4 lsA[(T > 1) ? 2 : 1][256];
  __shared__ uint4 lsB[(T > 1) ? 2 : 1][256];

  const int lane = threadIdx.x;
  const int mg = lane >> 3;      // 0..7 -> output rows mg*8 + r
  const int og = lane & 7;       // 0..7 -> output cols og*8 + c
  const int row0 = blockIdx.y * 64;
  const int col0 = blockIdx.x * 64;
  const int kb0  = blockIdx.z * (T * 32);
  const int srow = og * 8 + mg;  // staging source row for this lane (all batches)

  uint acc[8][8];
#pragma unroll
  for (int r = 0; r < 8; r++)
#pragma unroll
    for (int c = 0; c < 8; c++) acc[r][c] = 0xFC00FC00u;  // packed f16 -inf

  auto stage = [&](int buf, int kb) {
#pragma unroll
    for (int i = 0; i < 4; i++)
      gload16(A16 + (size_t)(row0 + srow) * INF_ + kb + i * 8, &lsA[buf][i * 64]);
#pragma unroll
    for (int i = 0; i < 4; i++)
      gload16(W16T + (size_t)(col0 + srow) * INF_ + kb + i * 8, &lsB[buf][i * 64]);
  };

  auto compute = [&](int buf) {
#pragma unroll
    for (int kq = 0; kq < 4; kq++) {
      uint4 av[8], bv[8];
#pragma unroll
      for (int r = 0; r < 8; r++) av[r] = lsA[buf][kq * 64 + r * 8 + mg];
#pragma unroll
      for (int c = 0; c < 8; c++) bv[c] = lsB[buf][kq * 64 + c * 8 + og];
#pragma unroll
      for (int r = 0; r < 8; r++)
#pragma unroll
        for (int c = 0; c < 8; c++) {
          uint t0, t1, t2, t3;
          PKMIN(t0, av[r].x, bv[c].x);
          PKMIN(t1, av[r].y, bv[c].y);
          PKMIN(t2, av[r].z, bv[c].z);
          PKMIN(t3, av[r].w, bv[c].w);
          PKMAX(t0, t0, t1);
          PKMAX(t2, t2, t3);
          PKMAX(t0, t0, t2);
          PKMAXA(acc[r][c], t0);
        }
    }
  };

  if (T == 1) {
    stage(0, kb0);
    asm volatile("s_waitcnt vmcnt(0)" ::: "memory");
    compute(0);
  } else {
    stage(0, kb0);
    stage(1, kb0 + 32);
    asm volatile("s_waitcnt vmcnt(8)" ::: "memory");  // buf0 landed, buf1 in flight
    compute(0);
    asm volatile("s_waitcnt vmcnt(0)" ::: "memory");
    compute(1);
  }

  // epilogue: fold packed (k-even, k-odd) halves, store 8 f16 per row
  ushort* pout = part + (size_t)blockIdx.z * (BATCH * OUTF);
#pragma unroll
  for (int r = 0; r < 8; r++) {
    uint w[4];
#pragma unroll
    for (int cp = 0; cp < 4; cp++) {
      uint x0 = acc[r][2 * cp], x1 = acc[r][2 * cp + 1];
      uint h0 = x0 >> 16, h1 = x1 >> 16, m0, m1;
      PKMAX(m0, x0, h0);
      PKMAX(m1, x1, h1);
      w[cp] = (m0 & 0xFFFFu) | (m1 << 16);
    }
    int row = row0 + mg * 8 + r;
    int col = col0 + og * 8;
    *(uint4*)(pout + (size_t)row * OUTF + col) = make_uint4(w[0], w[1], w[2], w[3]);
  }
}

// ---- pass 3: combine KS f16 planes -> f32 out ----
template <int KSP>
__global__ __launch_bounds__(256) void crisp_combine16(const uint4* __restrict__ part,
                                                       float* __restrict__ out) {
  int gid = blockIdx.x * 256 + threadIdx.x;  // 65536 threads x 8 outputs
  uint4 v = part[gid];
#pragma unroll
  for (int p = 1; p < KSP; p++) {
    uint4 u = part[(size_t)p * 65536 + gid];
    PKMAXA(v.x, u.x); PKMAXA(v.y, u.y); PKMAXA(v.z, u.z); PKMAXA(v.w, u.w);
  }
  float4 o0 = make_float4(h2f(v.x), h2f(v.x >> 16), h2f(v.y), h2f(v.y >> 16));
  float4 o1 = make_float4(h2f(v.z), h2f(v.z >> 16), h2f(v.w), h2f(v.w >> 16));
  ((float4*)out)[gid * 2]     = o0;
  ((float4*)out)[gid * 2 + 1] = o1;
}

// ---- fallback: naive, correct ----
__global__ __launch_bounds__(256) void crisp_naive(const float* __restrict__ M,
                                                   const float* __restrict__ W,
                                                   float* __restrict__ out) {
  int o = blockIdx.x * 256 + threadIdx.x;
  int b = o >> 8, c = o & 255;
  float m = -1e30f;
  for (int k = 0; k < INF_; k++)
    m = fmaxf(m, fminf(M[(size_t)b * INF_ + k], W[(size_t)k * OUTF + c]));
  out[o] = m;
}

extern "C" void kernel_launch(void* const* d_in, const int* in_sizes, int n_in,
                              void* d_out, int out_size, void* d_ws, size_t ws_size,
                              hipStream_t stream) {
  const float* M = (const float*)d_in[0];
  const float* W = (const float*)d_in[1];
  float* out = (float*)d_out;

  ushort* A16  = (ushort*)((char*)d_ws + A16_OFF);
  ushort* W16T = (ushort*)((char*)d_ws + W16T_OFF);
  ushort* part = (ushort*)((char*)d_ws + PART_OFF);

  if (ws_size >= PART_OFF + 16 * PLANE16) {
    // KS=16: 2048 one-wave blocks = 2 waves/SIMD
    crisp_convert<<<544, 256, 0, stream>>>(M, W, A16, W16T);
    crisp_partial16<1><<<dim3(OUTF / 64, BATCH / 64, 16), 64, 0, stream>>>(A16, W16T, part);
    crisp_combine16<16><<<256, 256, 0, stream>>>((const uint4*)part, out);
  } else if (ws_size >= PART_OFF + 8 * PLANE16) {
    // KS=8: 1024 blocks, double-buffered
    crisp_convert<<<544, 256, 0, stream>>>(M, W, A16, W16T);
    crisp_partial16<2><<<dim3(OUTF / 64, BATCH / 64, 8), 64, 0, stream>>>(A16, W16T, part);
    crisp_combine16<8><<<256, 256, 0, stream>>>((const uint4*)part, out);
  } else {
    crisp_naive<<<(BATCH * OUTF) / 256, 256, 0, stream>>>(M, W, out);
  }
}